// Round 2
// baseline (177.580 us; speedup 1.0000x reference)
//
#include <hip/hip_runtime.h>

// YOLOv3 decode, 3 scales fused. R2: float4 loads along hw for scales 26/52
// (HW divisible by 4) -> 85 global_load_dwordx4 per thread, class loop
// unrolled x16 for memory-level parallelism. Scale 13 (HW=169) stays scalar.
// grid.y = anchor; consecutive threads -> consecutive hw -> coalesced.

#define NCLS 80

template<int H, int W>
__device__ __forceinline__ void decode_vec4(
    const float* __restrict__ in, const float* __restrict__ anch,
    float scale, float inv_case, float th,
    int a, int t, int row_base,
    float* __restrict__ boxes, float* __restrict__ mask)
{
    constexpr int HW = H * W;
    constexpr int Q  = HW / 4;          // float4s per channel
    int b  = t / Q;                      // compile-time divisor -> magic mul
    int q  = t - b * Q;
    int hw = 4 * q;

    const float4* p = reinterpret_cast<const float4*>(
        in + ((size_t)b * 255 + (size_t)a * 85) * HW) + q;

    float4 o0 = p[0 * Q];
    float4 o1 = p[1 * Q];
    float4 o2 = p[2 * Q];
    float4 o3 = p[3 * Q];
    float4 o4 = p[4 * Q];

    float4 bv = p[5 * Q];
    float bs[4] = {bv.x, bv.y, bv.z, bv.w};
    float bi[4] = {0.f, 0.f, 0.f, 0.f};
#pragma unroll 16
    for (int d = 1; d < NCLS; ++d) {
        float4 v = p[(5 + d) * Q];
        if (v.x > bs[0]) { bs[0] = v.x; bi[0] = (float)d; }
        if (v.y > bs[1]) { bs[1] = v.y; bi[1] = (float)d; }
        if (v.z > bs[2]) { bs[2] = v.z; bi[2] = (float)d; }
        if (v.w > bs[3]) { bs[3] = v.w; bi[3] = (float)d; }
    }

    const float aw = anch[2 * a + 0] * inv_case;
    const float ah = anch[2 * a + 1] * inv_case;

    float O0[4] = {o0.x, o0.y, o0.z, o0.w};
    float O1[4] = {o1.x, o1.y, o1.z, o1.w};
    float O2[4] = {o2.x, o2.y, o2.z, o2.w};
    float O3[4] = {o3.x, o3.y, o3.z, o3.w};
    float O4[4] = {o4.x, o4.y, o4.z, o4.w};

#pragma unroll
    for (int j = 0; j < 4; ++j) {
        int hwj = hw + j;
        int h = hwj / W;                 // compile-time W -> magic mul
        int w = hwj - h * W;
        float px = 1.0f / (1.0f + __expf(-O0[j]));
        float cx = ((float)w + O1[j]) * scale;
        float cy = ((float)h + O2[j]) * scale;
        float bw = aw * __expf(O3[j]);
        float bh = ah * __expf(O4[j]);

        int row = row_base + (b * HW + hwj) * 3 + a;
        float* ob = boxes + (size_t)row * 6;
        ob[0] = px;
        ob[1] = cx;
        ob[2] = cy;
        ob[3] = bw;
        ob[4] = bh;
        ob[5] = bi[j];
        mask[row] = (O0[j] > th) ? 1.0f : 0.0f;
    }
}

template<int H, int W>
__device__ __forceinline__ void decode_scalar(
    const float* __restrict__ in, const float* __restrict__ anch,
    float scale, float inv_case, float th,
    int a, int cell, int row_base,
    float* __restrict__ boxes, float* __restrict__ mask)
{
    constexpr int HW = H * W;
    int b  = cell / HW;
    int hw = cell - b * HW;
    int h  = hw / W;
    int w  = hw - h * W;

    const float* p = in + ((size_t)b * 255 + (size_t)a * 85) * HW + hw;

    float o0 = p[0 * HW];
    float o1 = p[1 * HW];
    float o2 = p[2 * HW];
    float o3 = p[3 * HW];
    float o4 = p[4 * HW];

    float best = p[5 * HW];
    int   bi   = 0;
#pragma unroll 16
    for (int d = 1; d < NCLS; ++d) {
        float v = p[(5 + d) * HW];
        if (v > best) { best = v; bi = d; }
    }

    float px = 1.0f / (1.0f + __expf(-o0));
    float cx = ((float)w + o1) * scale;
    float cy = ((float)h + o2) * scale;
    float bw = anch[2 * a + 0] * __expf(o3) * inv_case;
    float bh = anch[2 * a + 1] * __expf(o4) * inv_case;

    int row = row_base + cell * 3 + a;
    float* ob = boxes + (size_t)row * 6;
    ob[0] = px;
    ob[1] = cx;
    ob[2] = cy;
    ob[3] = bw;
    ob[4] = bh;
    ob[5] = (float)bi;
    mask[row] = (o0 > th) ? 1.0f : 0.0f;
}

__global__ __launch_bounds__(256) void detector_kernel(
    const float* __restrict__ in13, const float* __restrict__ in26,
    const float* __restrict__ in52,
    const float* __restrict__ a13, const float* __restrict__ a26,
    const float* __restrict__ a52,
    const float* __restrict__ thp, const int* __restrict__ casep,
    float* __restrict__ boxes, float* __restrict__ mask,
    int B, int nb52, int nb26)
{
    const int a  = blockIdx.y;
    const int bx = blockIdx.x;
    const float th       = thp[0];
    const float inv_case = 1.0f / (float)casep[0];

    if (bx < nb52) {
        int t = bx * 256 + threadIdx.x;                 // t over B * 676 float4s
        if (t < B * (2704 / 4))
            decode_vec4<52, 52>(in52, a52, 8.0f * inv_case, inv_case, th,
                                a, t, B * (169 + 676) * 3, boxes, mask);
    } else if (bx < nb52 + nb26) {
        int t = (bx - nb52) * 256 + threadIdx.x;        // t over B * 169 float4s
        if (t < B * (676 / 4))
            decode_vec4<26, 26>(in26, a26, 16.0f * inv_case, inv_case, th,
                                a, t, B * 169 * 3, boxes, mask);
    } else {
        int cell = (bx - nb52 - nb26) * 256 + threadIdx.x;
        if (cell < B * 169)
            decode_scalar<13, 13>(in13, a13, 32.0f * inv_case, inv_case, th,
                                  a, cell, 0, boxes, mask);
    }
}

extern "C" void kernel_launch(void* const* d_in, const int* in_sizes, int n_in,
                              void* d_out, int out_size, void* d_ws, size_t ws_size,
                              hipStream_t stream) {
    const float* in13 = (const float*)d_in[0];
    const float* in26 = (const float*)d_in[1];
    const float* in52 = (const float*)d_in[2];
    const float* a13  = (const float*)d_in[3];
    const float* a26  = (const float*)d_in[4];
    const float* a52  = (const float*)d_in[5];
    const float* thp  = (const float*)d_in[6];
    const int*   casep = (const int*)d_in[7];

    const int B = in_sizes[0] / (255 * 169);

    const int nb52 = (B * (2704 / 4) + 255) / 256;   // float4 threads
    const int nb26 = (B * (676 / 4)  + 255) / 256;   // float4 threads
    const int nb13 = (B * 169        + 255) / 256;   // scalar threads

    const int nrows = B * (169 + 676 + 2704) * 3;
    float* boxes = (float*)d_out;
    float* mask  = (float*)d_out + (size_t)nrows * 6;

    dim3 grid(nb52 + nb26 + nb13, 3);
    detector_kernel<<<grid, 256, 0, stream>>>(
        in13, in26, in52, a13, a26, a52, thp, casep,
        boxes, mask, B, nb52, nb26);
}

// Round 3
// 174.928 us; speedup vs baseline: 1.0152x; 1.0152x over previous
//
#include <hip/hip_runtime.h>

// YOLOv3 decode, 3 scales fused. R3: back to R1's mapping (1 thread per
// (anchor, cell) -> 340k threads, ~21 waves/CU) but with explicit 20-wide
// load batches for the class argmax so each thread keeps 20 independent
// global_load_dword in flight (R1's VGPR=16 allowed only ~3).
// grid.y = anchor; consecutive threads -> consecutive hw -> coalesced.

#define NCLS 80
#define BATCH 20

template<int H, int W>
__device__ __forceinline__ void decode_scale(
    const float* __restrict__ in, const float* __restrict__ anch,
    float scale, float inv_case, float th,
    int a, int cell, int row_base,
    float* __restrict__ boxes, float* __restrict__ mask)
{
    constexpr int HW = H * W;
    int b  = cell / HW;          // compile-time divisor -> magic mul
    int hw = cell - b * HW;
    int h  = hw / W;
    int w  = hw - h * W;

    const float* p = in + ((size_t)b * 255 + (size_t)a * 85) * HW + hw;

    // box channels: 5 independent loads in flight
    float o0 = p[0 * HW];
    float o1 = p[1 * HW];
    float o2 = p[2 * HW];
    float o3 = p[3 * HW];
    float o4 = p[4 * HW];

    // class argmax: 4 batches of 20 independent loads, then compare.
    // strict > keeps first-max semantics (matches jnp.argmax).
    float best = -__builtin_inff();
    int   bi   = 0;
    const float* pc = p + 5 * HW;
#pragma unroll
    for (int g = 0; g < NCLS / BATCH; ++g) {
        float v[BATCH];
#pragma unroll
        for (int j = 0; j < BATCH; ++j)
            v[j] = pc[(g * BATCH + j) * HW];
#pragma unroll
        for (int j = 0; j < BATCH; ++j) {
            if (v[j] > best) { best = v[j]; bi = g * BATCH + j; }
        }
    }

    float px = 1.0f / (1.0f + __expf(-o0));
    float cx = ((float)w + o1) * scale;
    float cy = ((float)h + o2) * scale;
    float bw = anch[2 * a + 0] * __expf(o3) * inv_case;
    float bh = anch[2 * a + 1] * __expf(o4) * inv_case;

    int row = row_base + cell * 3 + a;
    // row*6 floats = row*24 B -> always 8B aligned: 3x float2 stores
    float2* ob = reinterpret_cast<float2*>(boxes + (size_t)row * 6);
    ob[0] = make_float2(px, cx);
    ob[1] = make_float2(cy, bw);
    ob[2] = make_float2(bh, (float)bi);
    mask[row] = (o0 > th) ? 1.0f : 0.0f;
}

__global__ __launch_bounds__(256) void detector_kernel(
    const float* __restrict__ in13, const float* __restrict__ in26,
    const float* __restrict__ in52,
    const float* __restrict__ a13, const float* __restrict__ a26,
    const float* __restrict__ a52,
    const float* __restrict__ thp, const int* __restrict__ casep,
    float* __restrict__ boxes, float* __restrict__ mask,
    int B, int nb52, int nb26)
{
    const int a  = blockIdx.y;
    const int bx = blockIdx.x;
    const float th       = thp[0];
    const float inv_case = 1.0f / (float)casep[0];

    if (bx < nb52) {
        int cell = bx * 256 + threadIdx.x;
        if (cell < B * 2704)
            decode_scale<52, 52>(in52, a52, 8.0f * inv_case, inv_case, th,
                                 a, cell, B * (169 + 676) * 3, boxes, mask);
    } else if (bx < nb52 + nb26) {
        int cell = (bx - nb52) * 256 + threadIdx.x;
        if (cell < B * 676)
            decode_scale<26, 26>(in26, a26, 16.0f * inv_case, inv_case, th,
                                 a, cell, B * 169 * 3, boxes, mask);
    } else {
        int cell = (bx - nb52 - nb26) * 256 + threadIdx.x;
        if (cell < B * 169)
            decode_scale<13, 13>(in13, a13, 32.0f * inv_case, inv_case, th,
                                 a, cell, 0, boxes, mask);
    }
}

extern "C" void kernel_launch(void* const* d_in, const int* in_sizes, int n_in,
                              void* d_out, int out_size, void* d_ws, size_t ws_size,
                              hipStream_t stream) {
    const float* in13 = (const float*)d_in[0];
    const float* in26 = (const float*)d_in[1];
    const float* in52 = (const float*)d_in[2];
    const float* a13  = (const float*)d_in[3];
    const float* a26  = (const float*)d_in[4];
    const float* a52  = (const float*)d_in[5];
    const float* thp  = (const float*)d_in[6];
    const int*   casep = (const int*)d_in[7];

    const int B = in_sizes[0] / (255 * 169);

    const int nb52 = (B * 2704 + 255) / 256;
    const int nb26 = (B * 676  + 255) / 256;
    const int nb13 = (B * 169  + 255) / 256;

    const int nrows = B * (169 + 676 + 2704) * 3;
    float* boxes = (float*)d_out;
    float* mask  = (float*)d_out + (size_t)nrows * 6;

    dim3 grid(nb52 + nb26 + nb13, 3);
    detector_kernel<<<grid, 256, 0, stream>>>(
        in13, in26, in52, a13, a26, a52, thp, casep,
        boxes, mask, B, nb52, nb26);
}

// Round 4
// 170.993 us; speedup vs baseline: 1.0385x; 1.0230x over previous
//
#include <hip/hip_runtime.h>
#include <stdint.h>

// YOLOv3 decode. R4: async global->LDS DMA staging.
// Evidence R1-R3: BW ~ waves/CU x bytes/VMEM-instr (register-destination
// loads sustain only ~1-2 in flight per wave regardless of batching).
// Fix: __builtin_amdgcn_global_load_lds queues up to 63 loads/wave with no
// dest registers. Block = (b, anchor, 128-cell hw tile): DMA 85ch x 128
// cells (42.5 KB) to LDS (~21 async 1-KB instrs/wave), sync, decode from
// LDS. 3 blocks/CU resident -> DMA of 2 blocks overlaps compute of 1.

#define NCLS 80
#define AS1 __attribute__((address_space(1)))
#define AS3 __attribute__((address_space(3)))

__device__ __forceinline__ void cp16_async(const float* g, float* l) {
    __builtin_amdgcn_global_load_lds((const AS1 void*)(uintptr_t)g,
                                     (AS3 void*)(uint32_t)(uintptr_t)l,
                                     16, 0, 0);
}

// One (b, anchor, tile) slab: 85 channels x CELLS cells staged via LDS.
// QPR = float4 quads per channel row (CELLS = 4*QPR). HW, QPR compile-time.
template<int HW, int QPR>
__device__ __forceinline__ void decode_tile(
    const float* __restrict__ in, const float* __restrict__ anch,
    float scale, float inv_case, float th,
    int b, int a, int hw0, int row_base,
    float* __restrict__ boxes, float* __restrict__ mask,
    float* smem)
{
    constexpr int CELLS = QPR * 4;
    constexpr int NU    = 85 * QPR;       // total float4 units in slab
    const int tid  = threadIdx.x;
    const int lane = tid & 63;
    const int wv   = tid >> 6;            // wave id (block = 128 thr)

    const float* slab = in + ((size_t)b * 255 + (size_t)a * 85) * HW + hw0;

    // async DMA: wave-instr covers 64 units; LDS dest = uniform base + lane*16
#pragma unroll
    for (int base = wv * 64; base < NU; base += 128) {
        int u = base + lane;
        int r = u / QPR;                  // constexpr divisor -> shifts/magic
        int q = u - r * QPR;
        const float* g = slab + (size_t)r * HW + q * 4;
        if (u < NU)
            cp16_async(g, &smem[base * 4]);
    }
    __syncthreads();                       // waits vmcnt(0) then barrier

    if (tid < CELLS) {
        float o0 = smem[0 * CELLS + tid];
        float o1 = smem[1 * CELLS + tid];
        float o2 = smem[2 * CELLS + tid];
        float o3 = smem[3 * CELLS + tid];
        float o4 = smem[4 * CELLS + tid];

        const float* pc = smem + 5 * CELLS + tid;
        float best = pc[0];
        int   bi   = 0;
#pragma unroll 16
        for (int d = 1; d < NCLS; ++d) {
            float v = pc[d * CELLS];
            if (v > best) { best = v; bi = d; }
        }

        int hw = hw0 + tid;
        int h  = hw / HW == 0 ? hw / (HW / (HW / 52 ? 52 : 1)) : 0; // placeholder avoided below
        (void)h;
        constexpr int W = (HW == 2704) ? 52 : (HW == 676) ? 26 : 13;
        int hy = hw / W;
        int wx = hw - hy * W;

        float px = 1.0f / (1.0f + __expf(-o0));
        float cx = ((float)wx + o1) * scale;
        float cy = ((float)hy + o2) * scale;
        float bw = anch[2 * a + 0] * __expf(o3) * inv_case;
        float bh = anch[2 * a + 1] * __expf(o4) * inv_case;

        int row = row_base + (b * HW + hw) * 3 + a;
        float2* ob = reinterpret_cast<float2*>(boxes + (size_t)row * 6);
        ob[0] = make_float2(px, cx);
        ob[1] = make_float2(cy, bw);
        ob[2] = make_float2(bh, (float)bi);
        mask[row] = (o0 > th) ? 1.0f : 0.0f;
    }
}

// scalar path for 13x13 (4.7% of data), R3 structure
__device__ __forceinline__ void decode_scalar13(
    const float* __restrict__ in, const float* __restrict__ anch,
    float scale, float inv_case, float th,
    int a, int cell, float* __restrict__ boxes, float* __restrict__ mask)
{
    constexpr int HW = 169;
    int b  = cell / HW;
    int hw = cell - b * HW;
    int h  = hw / 13;
    int w  = hw - h * 13;

    const float* p = in + ((size_t)b * 255 + (size_t)a * 85) * HW + hw;

    float o0 = p[0 * HW];
    float o1 = p[1 * HW];
    float o2 = p[2 * HW];
    float o3 = p[3 * HW];
    float o4 = p[4 * HW];

    float best = -__builtin_inff();
    int   bi   = 0;
    const float* pc = p + 5 * HW;
#pragma unroll
    for (int g = 0; g < 4; ++g) {
        float v[20];
#pragma unroll
        for (int j = 0; j < 20; ++j) v[j] = pc[(g * 20 + j) * HW];
#pragma unroll
        for (int j = 0; j < 20; ++j)
            if (v[j] > best) { best = v[j]; bi = g * 20 + j; }
    }

    float px = 1.0f / (1.0f + __expf(-o0));
    float cx = ((float)w + o1) * scale;
    float cy = ((float)h + o2) * scale;
    float bw = anch[2 * a + 0] * __expf(o3) * inv_case;
    float bh = anch[2 * a + 1] * __expf(o4) * inv_case;

    int row = cell * 3 + a;
    float2* ob = reinterpret_cast<float2*>(boxes + (size_t)row * 6);
    ob[0] = make_float2(px, cx);
    ob[1] = make_float2(cy, bw);
    ob[2] = make_float2(bh, (float)bi);
    mask[row] = (o0 > th) ? 1.0f : 0.0f;
}

__global__ __launch_bounds__(128) void detector_kernel(
    const float* __restrict__ in13, const float* __restrict__ in26,
    const float* __restrict__ in52,
    const float* __restrict__ a13, const float* __restrict__ a26,
    const float* __restrict__ a52,
    const float* __restrict__ thp, const int* __restrict__ casep,
    float* __restrict__ boxes, float* __restrict__ mask,
    int B, int base26, int base52)
{
    __shared__ float smem[85 * 128];   // 42.5 KB

    const int bx = blockIdx.x;
    const float th       = thp[0];
    const float inv_case = 1.0f / (float)casep[0];

    // block ranges (B=32): 52full=2016, 52tail=96, 26full=480, 26tail=96, 13=127
    const int n52f = B * 3 * 21;
    const int n52t = B * 3;
    const int n26f = B * 3 * 5;
    const int n26t = B * 3;

    if (bx < n52f) {
        int i = bx;
        int b = i / 63, r = i - b * 63;
        int a = r / 21, tl = r - a * 21;
        decode_tile<2704, 32>(in52, a52, 8.0f * inv_case, inv_case, th,
                              b, a, tl * 128, base52, boxes, mask, smem);
    } else if (bx < n52f + n52t) {
        int i = bx - n52f;
        int b = i / 3, a = i - b * 3;
        decode_tile<2704, 4>(in52, a52, 8.0f * inv_case, inv_case, th,
                             b, a, 2688, base52, boxes, mask, smem);
    } else if (bx < n52f + n52t + n26f) {
        int i = bx - n52f - n52t;
        int b = i / 15, r = i - b * 15;
        int a = r / 5, tl = r - a * 5;
        decode_tile<676, 32>(in26, a26, 16.0f * inv_case, inv_case, th,
                             b, a, tl * 128, base26, boxes, mask, smem);
    } else if (bx < n52f + n52t + n26f + n26t) {
        int i = bx - n52f - n52t - n26f;
        int b = i / 3, a = i - b * 3;
        decode_tile<676, 9>(in26, a26, 16.0f * inv_case, inv_case, th,
                            b, a, 640, base26, boxes, mask, smem);
    } else {
        int cf = (bx - n52f - n52t - n26f - n26t) * 128 + threadIdx.x;
        if (cf < B * 169 * 3) {
            int a = cf / (169 * 32);
            int r = cf - a * (169 * 32);     // r = b*169 + hw = cell
            decode_scalar13(in13, a13, 32.0f * inv_case, inv_case, th,
                            a, r, boxes, mask);
        }
    }
}

extern "C" void kernel_launch(void* const* d_in, const int* in_sizes, int n_in,
                              void* d_out, int out_size, void* d_ws, size_t ws_size,
                              hipStream_t stream) {
    const float* in13 = (const float*)d_in[0];
    const float* in26 = (const float*)d_in[1];
    const float* in52 = (const float*)d_in[2];
    const float* a13  = (const float*)d_in[3];
    const float* a26  = (const float*)d_in[4];
    const float* a52  = (const float*)d_in[5];
    const float* thp  = (const float*)d_in[6];
    const int*   casep = (const int*)d_in[7];

    const int B = in_sizes[0] / (255 * 169);

    const int base26 = B * 169 * 3;
    const int base52 = B * (169 + 676) * 3;

    const int n52 = B * 3 * 21 + B * 3;            // full + tail tiles
    const int n26 = B * 3 * 5 + B * 3;
    const int n13 = (B * 169 * 3 + 127) / 128;

    const int nrows = B * (169 + 676 + 2704) * 3;
    float* boxes = (float*)d_out;
    float* mask  = (float*)d_out + (size_t)nrows * 6;

    detector_kernel<<<n52 + n26 + n13, 128, 0, stream>>>(
        in13, in26, in52, a13, a26, a52, thp, casep,
        boxes, mask, B, base26, base52);
}

// Round 5
// 170.472 us; speedup vs baseline: 1.0417x; 1.0031x over previous
//
#include <hip/hip_runtime.h>

// YOLOv3 decode. R5: occupancy attack. R1-R4 all plateau at ~1.5 TB/s read
// BW (~34 outstanding lines/CU) with <=21 waves/CU; write-only fill hits
// 6.8 TB/s at full occupancy. Split each output row across 4 threads
// (seg = class block of 20; seg0 also box channels) -> 1.36M threads,
// ~83 waves/CU oversubscription, short per-thread body, VGPR ~50.
// Quad argmax reduce via __shfl_xor with first-max tie-break.

#define NCLS 80

template<int HW, int W>
__device__ __forceinline__ void decode4(
    const float* __restrict__ in, const float* __restrict__ anch,
    float scale, float inv_case, float th,
    int a, int t, int row_base, int B,
    float* __restrict__ boxes, float* __restrict__ mask)
{
    if (t >= B * HW * 4) return;
    const int rt  = t >> 2;          // row-in-scale-anchor: b*HW + hw
    const int seg = t & 3;           // class segment 0..3
    const int b   = rt / HW;         // compile-time divisor -> magic mul
    const int hw  = rt - b * HW;

    const float* p = in + ((size_t)b * 255 + (size_t)a * 85) * HW + hw;

    // 20 independent class loads for this segment, then compare.
    const float* pc = p + (size_t)(5 + seg * 20) * HW;
    float v[20];
#pragma unroll
    for (int j = 0; j < 20; ++j)
        v[j] = pc[(size_t)j * HW];

    float best = v[0];
    int   bi   = seg * 20;
#pragma unroll
    for (int j = 1; j < 20; ++j)
        if (v[j] > best) { best = v[j]; bi = seg * 20 + j; }

    // box channels: all 4 segs load the same addresses (same line -> free),
    // issued before the reduce so latency overlaps the shuffles.
    float o0 = p[0 * (size_t)HW];
    float o1 = p[1 * (size_t)HW];
    float o2 = p[2 * (size_t)HW];
    float o3 = p[3 * (size_t)HW];
    float o4 = p[4 * (size_t)HW];

    // quad butterfly reduce: max with smallest-index tie-break (jnp.argmax)
#pragma unroll
    for (int m = 1; m <= 2; m <<= 1) {
        float ob = __shfl_xor(best, m);
        int   oi = __shfl_xor(bi,   m);
        if (ob > best || (ob == best && oi < bi)) { best = ob; bi = oi; }
    }

    if (seg == 0) {
        int h = hw / W;
        int w = hw - h * W;
        float px = 1.0f / (1.0f + __expf(-o0));
        float cx = ((float)w + o1) * scale;
        float cy = ((float)h + o2) * scale;
        float bw = anch[2 * a + 0] * __expf(o3) * inv_case;
        float bh = anch[2 * a + 1] * __expf(o4) * inv_case;

        int row = row_base + rt * 3 + a;     // seg0 lanes -> 16 consecutive rt
        float2* ob2 = reinterpret_cast<float2*>(boxes + (size_t)row * 6);
        ob2[0] = make_float2(px, cx);
        ob2[1] = make_float2(cy, bw);
        ob2[2] = make_float2(bh, (float)bi);
        mask[row] = (o0 > th) ? 1.0f : 0.0f;
    }
}

__global__ __launch_bounds__(256) void detector_kernel(
    const float* __restrict__ in13, const float* __restrict__ in26,
    const float* __restrict__ in52,
    const float* __restrict__ a13, const float* __restrict__ a26,
    const float* __restrict__ a52,
    const float* __restrict__ thp, const int* __restrict__ casep,
    float* __restrict__ boxes, float* __restrict__ mask,
    int B, int nb52, int nb26)
{
    const int a  = blockIdx.y;
    const int bx = blockIdx.x;
    const float th       = thp[0];
    const float inv_case = 1.0f / (float)casep[0];

    if (bx < nb52) {
        int t = bx * 256 + threadIdx.x;
        decode4<2704, 52>(in52, a52, 8.0f * inv_case, inv_case, th,
                          a, t, B * (169 + 676) * 3, B, boxes, mask);
    } else if (bx < nb52 + nb26) {
        int t = (bx - nb52) * 256 + threadIdx.x;
        decode4<676, 26>(in26, a26, 16.0f * inv_case, inv_case, th,
                         a, t, B * 169 * 3, B, boxes, mask);
    } else {
        int t = (bx - nb52 - nb26) * 256 + threadIdx.x;
        decode4<169, 13>(in13, a13, 32.0f * inv_case, inv_case, th,
                         a, t, 0, B, boxes, mask);
    }
}

extern "C" void kernel_launch(void* const* d_in, const int* in_sizes, int n_in,
                              void* d_out, int out_size, void* d_ws, size_t ws_size,
                              hipStream_t stream) {
    const float* in13 = (const float*)d_in[0];
    const float* in26 = (const float*)d_in[1];
    const float* in52 = (const float*)d_in[2];
    const float* a13  = (const float*)d_in[3];
    const float* a26  = (const float*)d_in[4];
    const float* a52  = (const float*)d_in[5];
    const float* thp  = (const float*)d_in[6];
    const int*   casep = (const int*)d_in[7];

    const int B = in_sizes[0] / (255 * 169);

    const int nb52 = (B * 2704 * 4 + 255) / 256;
    const int nb26 = (B * 676  * 4 + 255) / 256;
    const int nb13 = (B * 169  * 4 + 255) / 256;

    const int nrows = B * (169 + 676 + 2704) * 3;
    float* boxes = (float*)d_out;
    float* mask  = (float*)d_out + (size_t)nrows * 6;

    dim3 grid(nb52 + nb26 + nb13, 3);
    detector_kernel<<<grid, 256, 0, stream>>>(
        in13, in26, in52, a13, a26, a52, thp, casep,
        boxes, mask, B, nb52, nb26);
}